// Round 8
// baseline (718.082 us; speedup 1.0000x reference)
//
#include <hip/hip_runtime.h>
#include <math.h>

// SingleRoIExtractor: 4-level FPN RoIAlign (mmdet legacy, aligned=False)
// R8 = R7 champion (sort + XCD-chunked gather, FETCH 380->107MB) + aligned
// corner-pair loads. R7 evidence: FETCH dropped 3.5x but dur 149->143 only
// -> limiter is the per-CU TA/L1 line-lookup path (~1 distinct 64B line per
// cycle per CU), identical for L2 hits and HBM misses. The gather paid two
// instructions per bilinear corner ((off) and (off+1)), double-billing every
// line. Now: one ALIGNED float4 (lvl0-2; planes 16B-aligned since HW%4==0)
// or float2 (lvl3) per corner covers both elements; lanes whose pair
// straddles the window (off&3==3, ~25%) take a lane-predicated scalar
// fixup (exec-masked -> ~half-line cost). Element picks are v_cndmask
// chains from channel-invariant m=off&3. Per-channel line-lookups
// ~335 -> ~210. No OOB: base window always inside the channel plane.
// Discriminator: per-line TA model -> -30-35%; flat per-instruction cost
// -> unchanged (model refuted, pivot to staged phase-merging).

#define OUT_SZ 7
#define NCH 256
#define NBINS 49
#define NGROUPS 4
#define SORT_N 2048          // bitonic capacity (pad to pow2); K=1024 here

// ============================ dispatch 1: sort ============================
__global__ __launch_bounds__(256, 8)
void roi_sort_kernel(const float* __restrict__ rois, int K, int N,
                     int* __restrict__ perm)
{
    __shared__ unsigned long long s[SORT_N];
    const int t = threadIdx.x;

    for (int i = t; i < N; i += 256) {
        unsigned key = 0xFFFFFFFFu;           // pad entries sort to the end
        if (i < K) {
            float rb = rois[i * 5 + 0];
            float x1 = rois[i * 5 + 1], y1 = rois[i * 5 + 2];
            float x2 = rois[i * 5 + 3], y2 = rois[i * 5 + 4];
            float scale = sqrtf((x2 - x1 + 1.0f) * (y2 - y1 + 1.0f));
            int lvl = (int)floorf(log2f(scale * (1.0f / 56.0f) + 1e-6f));
            lvl = lvl < 0 ? 0 : (lvl > 3 ? 3 : lvl);
            float ss = 1.0f / (float)(4 << lvl);
            float Wf = 1216.0f * ss, Hf = 800.0f * ss;
            float cx = 0.5f * (x1 + x2) * ss;
            float cy = 0.5f * (y1 + y2) * ss;
            float qxf = cx * (128.0f / Wf);
            float qyf = cy * (128.0f / Hf);
            int qx = (int)fminf(fmaxf(qxf, 0.0f), 127.0f);   // NaN-safe
            int qy = (int)fminf(fmaxf(qyf, 0.0f), 127.0f);
            unsigned m = 0;
#pragma unroll
            for (int bb = 0; bb < 7; ++bb)
                m |= (((unsigned)(qx >> bb) & 1u) << (2 * bb)) |
                     (((unsigned)(qy >> bb) & 1u) << (2 * bb + 1));
            unsigned img = (rb > 0.5f) ? 1u : 0u;
            key = (((img * 4u + (unsigned)lvl) << 14) | m);
        }
        s[i] = ((unsigned long long)key << 32) | (unsigned)i;
    }
    __syncthreads();

    for (int size = 2; size <= N; size <<= 1) {
        for (int stride = size >> 1; stride > 0; stride >>= 1) {
            for (int tid = t; tid < N / 2; tid += 256) {
                int lo = tid & (stride - 1);
                int i = ((tid - lo) << 1) + lo;
                int j = i + stride;
                bool asc = ((i & size) == 0);
                unsigned long long a = s[i], b = s[j];
                if ((a > b) == asc) { s[i] = b; s[j] = a; }
            }
            __syncthreads();
        }
    }

    for (int i = t; i < K; i += 256)
        perm[i] = (int)(unsigned)(s[i] & 0xFFFFFFFFu);
}

// ====================== dispatch 2: aligned-pair gather ====================
// A = aligned chunk width (4 for lvl0-2, 2 for lvl3).
template<int A>
__device__ __forceinline__ void gather_channels(
    const float* __restrict__ chp, float* __restrict__ outp,
    size_t chstep, const int* __restrict__ off,
    const float* __restrict__ lx, const float* __restrict__ ly,
    float wv00, float wv01, float wv10, float wv11)
{
    // channel-invariant pick indices / straddle flags
    int  m[8];
    bool st[8];
#pragma unroll
    for (int q = 0; q < 8; ++q) {
        m[q]  = off[q] & (A - 1);
        st[q] = (m[q] == A - 1);
    }
    int base[8];
#pragma unroll
    for (int q = 0; q < 8; ++q) base[q] = off[q] & ~(A - 1);

    const float* p = chp;
    float* o = outp;
#pragma unroll 2
    for (int i = 0; i < 16; ++i) {      // channels ch0, ch0+4, ..., ch0+60
        float h[8];
#pragma unroll
        for (int q = 0; q < 8; ++q) {
            float v0, v1;
            if (A == 4) {
                float4 qd = *(const float4*)(p + base[q]);
                float fq = 0.0f;
                if (st[q]) fq = p[off[q] + 1];          // exec-masked fixup
                v0 = (m[q] == 1) ? qd.y : (m[q] == 2) ? qd.z
                     : (m[q] == 3) ? qd.w : qd.x;
                v1 = (m[q] == 1) ? qd.z : (m[q] == 2) ? qd.w
                     : (m[q] == 3) ? fq  : qd.y;
            } else {
                float2 qd = *(const float2*)(p + base[q]);
                float fq = 0.0f;
                if (st[q]) fq = p[off[q] + 1];          // exec-masked fixup
                v0 = st[q] ? qd.y : qd.x;
                v1 = st[q] ? fq   : qd.y;
            }
            h[q] = fmaf(lx[q & 1], v1 - v0, v0);        // x-interp
        }
        // rows: h[0],h[1]=ry0 ; h[2],h[3]=ry0+1 ; h[4],h[5]=ry1 ; h[6],h[7]=ry1+1
        float s00 = fmaf(ly[0], h[2] - h[0], h[0]);
        float s01 = fmaf(ly[0], h[3] - h[1], h[1]);
        float s10 = fmaf(ly[1], h[6] - h[4], h[4]);
        float s11 = fmaf(ly[1], h[7] - h[5], h[5]);

        float acc = wv00 * s00 + wv01 * s01 + wv10 * s10 + wv11 * s11;
        *o = acc * 0.25f;

        p += chstep;
        o += 4 * NBINS;
    }
}

__global__ __launch_bounds__(256, 6)
void roi_align_direct(const float* __restrict__ f0, const float* __restrict__ f1,
                      const float* __restrict__ f2, const float* __restrict__ f3,
                      const float* __restrict__ rois,
                      const int* __restrict__ perm, int K,
                      float* __restrict__ out)
{
    // XCD-chunked bijective remap (m204): consecutive sorted indices stay on
    // one XCD (blocks dispatch round-robin: xcd ~ blockIdx.x % 8).
    int k;
    {
        const int orig = blockIdx.x;
        const int q = K >> 3, r = K & 7;
        const int xcd = orig & 7, pos = orig >> 3;
        int idx = (xcd < r ? xcd * (q + 1) : r * (q + 1) + (xcd - r) * q) + pos;
        k = perm ? perm[idx] : idx;
    }
    const int g = blockIdx.y;
    const int t = threadIdx.x;
    const int w    = t >> 6;   // wave id 0..3
    const int lane = t & 63;

    float rb   = rois[k * 5 + 0];
    float rix1 = rois[k * 5 + 1];
    float riy1 = rois[k * 5 + 2];
    float rix2 = rois[k * 5 + 3];
    float riy2 = rois[k * 5 + 4];

    float scale = sqrtf((rix2 - rix1 + 1.0f) * (riy2 - riy1 + 1.0f));
    int lvl = (int)floorf(log2f(scale * (1.0f / 56.0f) + 1e-6f));
    lvl = lvl < 0 ? 0 : (lvl > 3 ? 3 : lvl);

    float ss = 1.0f / (float)(4 << lvl);
    float x1 = rix1 * ss, y1 = riy1 * ss;
    float rw = fmaxf(rix2 * ss - x1, 1.0f);
    float rh = fmaxf(riy2 * ss - y1, 1.0f);
    float bw = rw * (1.0f / OUT_SZ);
    float bh = rh * (1.0f / OUT_SZ);
    const int H = 800  >> (2 + lvl);
    const int W = 1216 >> (2 + lvl);
    const float fH = (float)H, fW = (float)W;
    const float* fb = (lvl == 0) ? f0 : (lvl == 1) ? f1 : (lvl == 2) ? f2 : f3;
    const int HW = H * W;

    if (lane >= NBINS) return;   // no barriers anywhere -> early exit is safe
    const int bin = lane;
    const int oy = bin / OUT_SZ;
    const int ox = bin - oy * OUT_SZ;

    // ---- per-lane sample geometry (computed once, reused for 16 channels) ----
    float lx[2], fvx[2]; int cx[2];
#pragma unroll
    for (int j = 0; j < 2; ++j) {
        float xs = x1 + ((float)(2 * ox + j) + 0.5f) * 0.5f * bw;
        fvx[j] = (xs >= -1.0f && xs <= fW) ? 1.0f : 0.0f;
        float xc = fminf(fmaxf(xs, 0.0f), fW - 1.0f);
        int x0 = (int)floorf(xc);
        x0 = min(x0, W - 2);            // xc=W-1 -> lx=1.0 selects col W-1
        lx[j] = xc - (float)x0;
        cx[j] = x0;
    }
    float ly[2], fvy[2]; int ry[2];
#pragma unroll
    for (int i = 0; i < 2; ++i) {
        float ysv = y1 + ((float)(2 * oy + i) + 0.5f) * 0.5f * bh;
        fvy[i] = (ysv >= -1.0f && ysv <= fH) ? 1.0f : 0.0f;
        float yc = fminf(fmaxf(ysv, 0.0f), fH - 1.0f);
        int y0 = (int)floorf(yc);
        y0 = min(y0, H - 2);            // yc=H-1 -> ly=1.0 selects row H-1
        ly[i] = yc - (float)y0;
        ry[i] = y0;
    }
    float wv00 = fvy[0] * fvx[0], wv01 = fvy[0] * fvx[1];
    float wv10 = fvy[1] * fvx[0], wv11 = fvy[1] * fvx[1];

    // 8 corner offsets: rows {ry0, ry0+1, ry1, ry1+1} x cols {cx0, cx1}.
    int off[8];
#pragma unroll
    for (int r = 0; r < 4; ++r) {
        int row = ry[r >> 1] + (r & 1);
        off[2 * r + 0] = row * W + cx[0];
        off[2 * r + 1] = row * W + cx[1];
    }

    const int ch0 = g * 64 + w;         // this wave's first channel
    const float* chp = fb + (size_t)((int)rb * NCH + ch0) * HW;
    float* outp = out + ((size_t)k * NCH + ch0) * NBINS + bin;

    if (HW & 3) {   // level 3: HW=950, planes only 8B-aligned -> float2
        gather_channels<2>(chp, outp, 4 * (size_t)HW, off, lx, ly,
                           wv00, wv01, wv10, wv11);
    } else {        // levels 0-2: planes 16B-aligned -> float4
        gather_channels<4>(chp, outp, 4 * (size_t)HW, off, lx, ly,
                           wv00, wv01, wv10, wv11);
    }
}

// ================================ launch ==================================
extern "C" void kernel_launch(void* const* d_in, const int* in_sizes, int n_in,
                              void* d_out, int out_size, void* d_ws, size_t ws_size,
                              hipStream_t stream)
{
    const float* f0   = (const float*)d_in[0];
    const float* f1   = (const float*)d_in[1];
    const float* f2   = (const float*)d_in[2];
    const float* f3   = (const float*)d_in[3];
    const float* rois = (const float*)d_in[4];
    float* out = (float*)d_out;

    int K = in_sizes[4] / 5;
    if (K <= 0) return;

    int* perm = nullptr;
    if (K <= SORT_N && d_ws && ws_size >= (size_t)K * sizeof(int)) {
        perm = (int*)d_ws;
        int N = 1;
        while (N < K) N <<= 1;          // pad to pow2 (<= SORT_N)
        roi_sort_kernel<<<1, 256, 0, stream>>>(rois, K, N, perm);
    }

    roi_align_direct<<<dim3(K, NGROUPS), 256, 0, stream>>>(
        f0, f1, f2, f3, rois, perm, K, out);
}

// Round 9
// 558.321 us; speedup vs baseline: 1.2861x; 1.2861x over previous
//
#include <hip/hip_runtime.h>
#include <math.h>

// SingleRoIExtractor: 4-level FPN RoIAlign (mmdet legacy, aligned=False)
// R9 = R7 champion (sort + XCD-chunked gather, FETCH 380->107MB) + aligned
// corner-pair loads, REDONE without R8's scratch bug. R8 post-mortem:
// passing local arrays (off[8], lx[2]) by pointer into a helper defeated
// SROA -> arrays in scratch -> FETCH 757MB / WRITE 229MB / 553us. This
// version keeps EVERYTHING in one kernel body as named scalars.
// Key simplification: W % A == 0 at every level, so off&(A-1) = cx&(A-1)
// is row-invariant -> only 2 alignment phases (one per column). Per column:
// a weight-quad wq (one-hot-pair of (1-lx, lx) at phase m, fvx folded) and
// a fixup weight wf (nonzero only when m==A-1). Per corner: one ALIGNED
// float4 (lvl0-2) / float2 (lvl3) + dot4 + predicated 1-dword fixup
// (straddle lanes only, ~12/49). acc = sum_r wr_r*(D_r0+D_r1), with
// fvy/ly/0.25 folded into 4 row weights. No local arrays, no selects in
// the channel loop. Lines per channel ~272 -> ~190 (aligned quad never
// crosses a 64B line; fixup runs quarter-exec).
// Window safety: base=off&~(A-1) >= 0, base+A-1 <= HW-1 (HW%A==0), and
// fixup off+1 <= HW-1 always -> no OOB even for the tensor's last plane.

#define OUT_SZ 7
#define NCH 256
#define NBINS 49
#define NGROUPS 4
#define SORT_N 2048          // bitonic capacity (pad to pow2); K=1024 here

// ============================ dispatch 1: sort ============================
__global__ __launch_bounds__(256, 8)
void roi_sort_kernel(const float* __restrict__ rois, int K, int N,
                     int* __restrict__ perm)
{
    __shared__ unsigned long long s[SORT_N];
    const int t = threadIdx.x;

    for (int i = t; i < N; i += 256) {
        unsigned key = 0xFFFFFFFFu;           // pad entries sort to the end
        if (i < K) {
            float rb = rois[i * 5 + 0];
            float x1 = rois[i * 5 + 1], y1 = rois[i * 5 + 2];
            float x2 = rois[i * 5 + 3], y2 = rois[i * 5 + 4];
            float scale = sqrtf((x2 - x1 + 1.0f) * (y2 - y1 + 1.0f));
            int lvl = (int)floorf(log2f(scale * (1.0f / 56.0f) + 1e-6f));
            lvl = lvl < 0 ? 0 : (lvl > 3 ? 3 : lvl);
            float ss = 1.0f / (float)(4 << lvl);
            float Wf = 1216.0f * ss, Hf = 800.0f * ss;
            float cx = 0.5f * (x1 + x2) * ss;
            float cy = 0.5f * (y1 + y2) * ss;
            float qxf = cx * (128.0f / Wf);
            float qyf = cy * (128.0f / Hf);
            int qx = (int)fminf(fmaxf(qxf, 0.0f), 127.0f);   // NaN-safe
            int qy = (int)fminf(fmaxf(qyf, 0.0f), 127.0f);
            unsigned m = 0;
#pragma unroll
            for (int bb = 0; bb < 7; ++bb)
                m |= (((unsigned)(qx >> bb) & 1u) << (2 * bb)) |
                     (((unsigned)(qy >> bb) & 1u) << (2 * bb + 1));
            unsigned img = (rb > 0.5f) ? 1u : 0u;
            key = (((img * 4u + (unsigned)lvl) << 14) | m);
        }
        s[i] = ((unsigned long long)key << 32) | (unsigned)i;
    }
    __syncthreads();

    for (int size = 2; size <= N; size <<= 1) {
        for (int stride = size >> 1; stride > 0; stride >>= 1) {
            for (int tid = t; tid < N / 2; tid += 256) {
                int lo = tid & (stride - 1);
                int i = ((tid - lo) << 1) + lo;
                int j = i + stride;
                bool asc = ((i & size) == 0);
                unsigned long long a = s[i], b = s[j];
                if ((a > b) == asc) { s[i] = b; s[j] = a; }
            }
            __syncthreads();
        }
    }

    for (int i = t; i < K; i += 256)
        perm[i] = (int)(unsigned)(s[i] & 0xFFFFFFFFu);
}

// ====================== dispatch 2: aligned-pair gather ====================
__global__ __launch_bounds__(256, 5)
void roi_align_direct(const float* __restrict__ f0, const float* __restrict__ f1,
                      const float* __restrict__ f2, const float* __restrict__ f3,
                      const float* __restrict__ rois,
                      const int* __restrict__ perm, int K,
                      float* __restrict__ out)
{
    // XCD-chunked bijective remap (m204): consecutive sorted indices stay on
    // one XCD (blocks dispatch round-robin: xcd ~ blockIdx.x % 8).
    int k;
    {
        const int orig = blockIdx.x;
        const int q = K >> 3, r = K & 7;
        const int xcd = orig & 7, pos = orig >> 3;
        int idx = (xcd < r ? xcd * (q + 1) : r * (q + 1) + (xcd - r) * q) + pos;
        k = perm ? perm[idx] : idx;
    }
    const int g = blockIdx.y;
    const int t = threadIdx.x;
    const int w    = t >> 6;   // wave id 0..3
    const int lane = t & 63;

    float rb   = rois[k * 5 + 0];
    float rix1 = rois[k * 5 + 1];
    float riy1 = rois[k * 5 + 2];
    float rix2 = rois[k * 5 + 3];
    float riy2 = rois[k * 5 + 4];

    float scale = sqrtf((rix2 - rix1 + 1.0f) * (riy2 - riy1 + 1.0f));
    int lvl = (int)floorf(log2f(scale * (1.0f / 56.0f) + 1e-6f));
    lvl = lvl < 0 ? 0 : (lvl > 3 ? 3 : lvl);

    float ss = 1.0f / (float)(4 << lvl);
    float x1 = rix1 * ss, y1 = riy1 * ss;
    float rw = fmaxf(rix2 * ss - x1, 1.0f);
    float rh = fmaxf(riy2 * ss - y1, 1.0f);
    float bw = rw * (1.0f / OUT_SZ);
    float bh = rh * (1.0f / OUT_SZ);
    const int H = 800  >> (2 + lvl);
    const int W = 1216 >> (2 + lvl);
    const float fH = (float)H, fW = (float)W;
    const float* fb = (lvl == 0) ? f0 : (lvl == 1) ? f1 : (lvl == 2) ? f2 : f3;
    const int HW = H * W;

    if (lane >= NBINS) return;   // no barriers anywhere -> early exit is safe
    const int bin = lane;
    const int oy = bin / OUT_SZ;
    const int ox = bin - oy * OUT_SZ;

    // ---- x geometry (named scalars only) ----
    float xs0 = x1 + ((float)(2 * ox + 0) + 0.5f) * 0.5f * bw;
    float xs1 = x1 + ((float)(2 * ox + 1) + 0.5f) * 0.5f * bw;
    float fvx0 = (xs0 >= -1.0f && xs0 <= fW) ? 1.0f : 0.0f;
    float fvx1 = (xs1 >= -1.0f && xs1 <= fW) ? 1.0f : 0.0f;
    float xc0 = fminf(fmaxf(xs0, 0.0f), fW - 1.0f);
    float xc1 = fminf(fmaxf(xs1, 0.0f), fW - 1.0f);
    int cx0 = min((int)floorf(xc0), W - 2);
    int cx1 = min((int)floorf(xc1), W - 2);
    float l0 = xc0 - (float)cx0;         // lx in [0,1]; =1.0 at right edge
    float l1 = xc1 - (float)cx1;

    // ---- y geometry ----
    float ys0 = y1 + ((float)(2 * oy + 0) + 0.5f) * 0.5f * bh;
    float ys1 = y1 + ((float)(2 * oy + 1) + 0.5f) * 0.5f * bh;
    float fvy0 = (ys0 >= -1.0f && ys0 <= fH) ? 1.0f : 0.0f;
    float fvy1 = (ys1 >= -1.0f && ys1 <= fH) ? 1.0f : 0.0f;
    float yc0 = fminf(fmaxf(ys0, 0.0f), fH - 1.0f);
    float yc1 = fminf(fmaxf(ys1, 0.0f), fH - 1.0f);
    int ry0 = min((int)floorf(yc0), H - 2);
    int ry1 = min((int)floorf(yc1), H - 2);
    float ly0 = yc0 - (float)ry0;
    float ly1 = yc1 - (float)ry1;

    // row weights (fvy, 0.25 folded); rows r0=ry0, r1=ry0+1, r2=ry1, r3=ry1+1
    float wr0 = 0.25f * fvy0 * (1.0f - ly0);
    float wr1 = 0.25f * fvy0 * ly0;
    float wr2 = 0.25f * fvy1 * (1.0f - ly1);
    float wr3 = 0.25f * fvy1 * ly1;

    int ro0 = ry0 * W, ro1 = ro0 + W;
    int ro2 = ry1 * W, ro3 = ro2 + W;

    const int ch0 = g * 64 + w;         // this wave's first channel
    const float* chp = fb + (size_t)((int)rb * NCH + ch0) * HW;
    float* outp = out + ((size_t)k * NCH + ch0) * NBINS + bin;
    const size_t chstep = 4 * (size_t)HW;

    if ((HW & 3) == 0) {
        // ================= levels 0-2: A=4, W%4==0 =================
        // alignment phase is row-invariant: m_j = cx_j & 3
        int m0 = cx0 & 3, m1 = cx1 & 3;
        int ax0 = cx0 - m0, ax1 = cx1 - m1;
        bool st0 = (m0 == 3), st1 = (m1 == 3);
        // column weight quads, fvx folded; fixup weight for straddle
        float wq00 = fvx0 * ((m0 == 0) ? (1.0f - l0) : 0.0f);
        float wq01 = fvx0 * ((m0 == 0) ? l0 : (m0 == 1) ? (1.0f - l0) : 0.0f);
        float wq02 = fvx0 * ((m0 == 1) ? l0 : (m0 == 2) ? (1.0f - l0) : 0.0f);
        float wq03 = fvx0 * ((m0 == 2) ? l0 : (m0 == 3) ? (1.0f - l0) : 0.0f);
        float wf0  = fvx0 * ((m0 == 3) ? l0 : 0.0f);
        float wq10 = fvx1 * ((m1 == 0) ? (1.0f - l1) : 0.0f);
        float wq11 = fvx1 * ((m1 == 0) ? l1 : (m1 == 1) ? (1.0f - l1) : 0.0f);
        float wq12 = fvx1 * ((m1 == 1) ? l1 : (m1 == 2) ? (1.0f - l1) : 0.0f);
        float wq13 = fvx1 * ((m1 == 2) ? l1 : (m1 == 3) ? (1.0f - l1) : 0.0f);
        float wf1  = fvx1 * ((m1 == 3) ? l1 : 0.0f);

        // 8 quad bases + 8 fixup offsets, all named scalars
        int b00 = ro0 + ax0, b01 = ro0 + ax1;
        int b10 = ro1 + ax0, b11 = ro1 + ax1;
        int b20 = ro2 + ax0, b21 = ro2 + ax1;
        int b30 = ro3 + ax0, b31 = ro3 + ax1;
        int x00 = ro0 + cx0 + 1, x01 = ro0 + cx1 + 1;
        int x10 = ro1 + cx0 + 1, x11 = ro1 + cx1 + 1;
        int x20 = ro2 + cx0 + 1, x21 = ro2 + cx1 + 1;
        int x30 = ro3 + cx0 + 1, x31 = ro3 + cx1 + 1;

        const float* p = chp;
        float* o = outp;
#pragma unroll 2
        for (int i = 0; i < 16; ++i) {   // channels ch0, ch0+4, ..., ch0+60
            // issue all 8 aligned quad loads first (ILP)
            float4 Q00 = *(const float4*)(p + b00);
            float4 Q01 = *(const float4*)(p + b01);
            float4 Q10 = *(const float4*)(p + b10);
            float4 Q11 = *(const float4*)(p + b11);
            float4 Q20 = *(const float4*)(p + b20);
            float4 Q21 = *(const float4*)(p + b21);
            float4 Q30 = *(const float4*)(p + b30);
            float4 Q31 = *(const float4*)(p + b31);
            // predicated straddle fixups (quarter-exec typical)
            float g00 = st0 ? p[x00] : 0.0f;
            float g10 = st0 ? p[x10] : 0.0f;
            float g20 = st0 ? p[x20] : 0.0f;
            float g30 = st0 ? p[x30] : 0.0f;
            float g01 = st1 ? p[x01] : 0.0f;
            float g11 = st1 ? p[x11] : 0.0f;
            float g21 = st1 ? p[x21] : 0.0f;
            float g31 = st1 ? p[x31] : 0.0f;

            float d00 = Q00.x*wq00 + Q00.y*wq01 + Q00.z*wq02 + Q00.w*wq03 + g00*wf0;
            float d01 = Q01.x*wq10 + Q01.y*wq11 + Q01.z*wq12 + Q01.w*wq13 + g01*wf1;
            float d10 = Q10.x*wq00 + Q10.y*wq01 + Q10.z*wq02 + Q10.w*wq03 + g10*wf0;
            float d11 = Q11.x*wq10 + Q11.y*wq11 + Q11.z*wq12 + Q11.w*wq13 + g11*wf1;
            float d20 = Q20.x*wq00 + Q20.y*wq01 + Q20.z*wq02 + Q20.w*wq03 + g20*wf0;
            float d21 = Q21.x*wq10 + Q21.y*wq11 + Q21.z*wq12 + Q21.w*wq13 + g21*wf1;
            float d30 = Q30.x*wq00 + Q30.y*wq01 + Q30.z*wq02 + Q30.w*wq03 + g30*wf0;
            float d31 = Q31.x*wq10 + Q31.y*wq11 + Q31.z*wq12 + Q31.w*wq13 + g31*wf1;

            float acc = wr0 * (d00 + d01) + wr1 * (d10 + d11)
                      + wr2 * (d20 + d21) + wr3 * (d30 + d31);
            *o = acc;
            p += chstep;
            o += 4 * NBINS;
        }
    } else {
        // ================= level 3: A=2, W%2==0 (W=38) =================
        int m0 = cx0 & 1, m1 = cx1 & 1;
        int ax0 = cx0 - m0, ax1 = cx1 - m1;
        bool st0 = (m0 == 1), st1 = (m1 == 1);
        float wq00 = fvx0 * ((m0 == 0) ? (1.0f - l0) : 0.0f);
        float wq01 = fvx0 * ((m0 == 0) ? l0 : (1.0f - l0));
        float wf0  = fvx0 * ((m0 == 1) ? l0 : 0.0f);
        float wq10 = fvx1 * ((m1 == 0) ? (1.0f - l1) : 0.0f);
        float wq11 = fvx1 * ((m1 == 0) ? l1 : (1.0f - l1));
        float wf1  = fvx1 * ((m1 == 1) ? l1 : 0.0f);

        int b00 = ro0 + ax0, b01 = ro0 + ax1;
        int b10 = ro1 + ax0, b11 = ro1 + ax1;
        int b20 = ro2 + ax0, b21 = ro2 + ax1;
        int b30 = ro3 + ax0, b31 = ro3 + ax1;
        int x00 = ro0 + cx0 + 1, x01 = ro0 + cx1 + 1;
        int x10 = ro1 + cx0 + 1, x11 = ro1 + cx1 + 1;
        int x20 = ro2 + cx0 + 1, x21 = ro2 + cx1 + 1;
        int x30 = ro3 + cx0 + 1, x31 = ro3 + cx1 + 1;

        const float* p = chp;
        float* o = outp;
#pragma unroll 2
        for (int i = 0; i < 16; ++i) {
            float2 Q00 = *(const float2*)(p + b00);
            float2 Q01 = *(const float2*)(p + b01);
            float2 Q10 = *(const float2*)(p + b10);
            float2 Q11 = *(const float2*)(p + b11);
            float2 Q20 = *(const float2*)(p + b20);
            float2 Q21 = *(const float2*)(p + b21);
            float2 Q30 = *(const float2*)(p + b30);
            float2 Q31 = *(const float2*)(p + b31);
            float g00 = st0 ? p[x00] : 0.0f;
            float g10 = st0 ? p[x10] : 0.0f;
            float g20 = st0 ? p[x20] : 0.0f;
            float g30 = st0 ? p[x30] : 0.0f;
            float g01 = st1 ? p[x01] : 0.0f;
            float g11 = st1 ? p[x11] : 0.0f;
            float g21 = st1 ? p[x21] : 0.0f;
            float g31 = st1 ? p[x31] : 0.0f;

            float d00 = Q00.x*wq00 + Q00.y*wq01 + g00*wf0;
            float d01 = Q01.x*wq10 + Q01.y*wq11 + g01*wf1;
            float d10 = Q10.x*wq00 + Q10.y*wq01 + g10*wf0;
            float d11 = Q11.x*wq10 + Q11.y*wq11 + g11*wf1;
            float d20 = Q20.x*wq00 + Q20.y*wq01 + g20*wf0;
            float d21 = Q21.x*wq10 + Q21.y*wq11 + g21*wf1;
            float d30 = Q30.x*wq00 + Q30.y*wq01 + g30*wf0;
            float d31 = Q31.x*wq10 + Q31.y*wq11 + g31*wf1;

            float acc = wr0 * (d00 + d01) + wr1 * (d10 + d11)
                      + wr2 * (d20 + d21) + wr3 * (d30 + d31);
            *o = acc;
            p += chstep;
            o += 4 * NBINS;
        }
    }
}

// ================================ launch ==================================
extern "C" void kernel_launch(void* const* d_in, const int* in_sizes, int n_in,
                              void* d_out, int out_size, void* d_ws, size_t ws_size,
                              hipStream_t stream)
{
    const float* f0   = (const float*)d_in[0];
    const float* f1   = (const float*)d_in[1];
    const float* f2   = (const float*)d_in[2];
    const float* f3   = (const float*)d_in[3];
    const float* rois = (const float*)d_in[4];
    float* out = (float*)d_out;

    int K = in_sizes[4] / 5;
    if (K <= 0) return;

    int* perm = nullptr;
    if (K <= SORT_N && d_ws && ws_size >= (size_t)K * sizeof(int)) {
        perm = (int*)d_ws;
        int N = 1;
        while (N < K) N <<= 1;          // pad to pow2 (<= SORT_N)
        roi_sort_kernel<<<1, 256, 0, stream>>>(rois, K, N, perm);
    }

    roi_align_direct<<<dim3(K, NGROUPS), 256, 0, stream>>>(
        f0, f1, f2, f3, rois, perm, K, out);
}

// Round 10
// 333.801 us; speedup vs baseline: 2.1512x; 1.6726x over previous
//
#include <hip/hip_runtime.h>
#include <math.h>

// SingleRoIExtractor: 4-level FPN RoIAlign (mmdet legacy, aligned=False)
// R10 = R7 sort+gather champion, with (a) aligned corner-pair quad loads
// (third attempt: R8 failed via array-by-pointer scratch, R9 failed via
// unroll2+tight-VGPR-cap spill -> WRITE 193MB smoking gun) and (b) bitonic
// sort (66 barrier rounds, ~16us) replaced by 1-block counting sort
// (histogram + Hillis-Steele scan + atomic scatter, ~23 barriers, ~4us).
// Spill-proofing: #pragma unroll 1 (only 8 quads = 32 VGPR live),
// __launch_bounds__(256,4) (cap 128 >> ~95 demand), all named scalars.
// Math identical to R9 (passed): per corner column with phase m=cx&A-1
// (row-invariant since W%A==0), weight-quad wq one-hot-pair of (1-lx,lx),
// straddle fixup (m==A-1) carries lx; rows fold fvy*ly*0.25 into 4 wr.
// Validity gates this round: WRITE ~51MB, FETCH ~110MB (scratch gone).

#define OUT_SZ 7
#define NCH 256
#define NBINS 49
#define NGROUPS 4
#define NBUCK 1024           // counting-sort buckets; block = 1024 threads

// ====================== dispatch 1: counting sort =========================
// key = img(1) : lvl(2) : morton_top7  -> 10 bits -> 1024 buckets.
// perm[pos] = original index of pos-th roi in sorted order.
__global__ __launch_bounds__(1024, 1)
void roi_sort_kernel(const float* __restrict__ rois, int K,
                     int* __restrict__ perm)
{
    __shared__ int cnt[NBUCK];
    __shared__ int ofs[NBUCK];
    const int t = threadIdx.x;

    cnt[t] = 0;
    __syncthreads();

    int mykey = 0;
    if (t < K) {
        float rb = rois[t * 5 + 0];
        float x1 = rois[t * 5 + 1], y1 = rois[t * 5 + 2];
        float x2 = rois[t * 5 + 3], y2 = rois[t * 5 + 4];
        float scale = sqrtf((x2 - x1 + 1.0f) * (y2 - y1 + 1.0f));
        int lvl = (int)floorf(log2f(scale * (1.0f / 56.0f) + 1e-6f));
        lvl = lvl < 0 ? 0 : (lvl > 3 ? 3 : lvl);
        float ss = 1.0f / (float)(4 << lvl);
        float Wf = 1216.0f * ss, Hf = 800.0f * ss;
        float cx = 0.5f * (x1 + x2) * ss;
        float cy = 0.5f * (y1 + y2) * ss;
        int qx = (int)fminf(fmaxf(cx * (128.0f / Wf), 0.0f), 127.0f);
        int qy = (int)fminf(fmaxf(cy * (128.0f / Hf), 0.0f), 127.0f);
        unsigned m14 = 0;
#pragma unroll
        for (int bb = 0; bb < 7; ++bb)
            m14 |= (((unsigned)(qx >> bb) & 1u) << (2 * bb)) |
                   (((unsigned)(qy >> bb) & 1u) << (2 * bb + 1));
        unsigned img = (rb > 0.5f) ? 1u : 0u;
        mykey = (int)(((img * 4u + (unsigned)lvl) << 7) | (m14 >> 7));
        atomicAdd(&cnt[mykey], 1);
    }
    __syncthreads();

    // inclusive Hillis-Steele scan over 1024 bins (all threads participate)
    int orig = cnt[t];
    int run  = orig;
    for (int d = 1; d < NBUCK; d <<= 1) {
        int u = (t >= d) ? cnt[t - d] : 0;
        __syncthreads();
        run += u;
        cnt[t] = run;
        __syncthreads();
    }
    ofs[t] = run - orig;          // exclusive prefix = bucket start
    __syncthreads();

    if (t < K) {
        int pos = atomicAdd(&ofs[mykey], 1);
        perm[pos] = t;
    }
}

// ====================== dispatch 2: aligned-pair gather ====================
__global__ __launch_bounds__(256, 4)
void roi_align_direct(const float* __restrict__ f0, const float* __restrict__ f1,
                      const float* __restrict__ f2, const float* __restrict__ f3,
                      const float* __restrict__ rois,
                      const int* __restrict__ perm, int K,
                      float* __restrict__ out)
{
    // XCD-chunked bijective remap (m204): consecutive sorted indices stay on
    // one XCD (blocks dispatch round-robin: xcd ~ blockIdx.x % 8).
    int k;
    {
        const int orig = blockIdx.x;
        const int q = K >> 3, r = K & 7;
        const int xcd = orig & 7, pos = orig >> 3;
        int idx = (xcd < r ? xcd * (q + 1) : r * (q + 1) + (xcd - r) * q) + pos;
        k = perm ? perm[idx] : idx;
    }
    const int g = blockIdx.y;
    const int t = threadIdx.x;
    const int w    = t >> 6;   // wave id 0..3
    const int lane = t & 63;

    float rb   = rois[k * 5 + 0];
    float rix1 = rois[k * 5 + 1];
    float riy1 = rois[k * 5 + 2];
    float rix2 = rois[k * 5 + 3];
    float riy2 = rois[k * 5 + 4];

    float scale = sqrtf((rix2 - rix1 + 1.0f) * (riy2 - riy1 + 1.0f));
    int lvl = (int)floorf(log2f(scale * (1.0f / 56.0f) + 1e-6f));
    lvl = lvl < 0 ? 0 : (lvl > 3 ? 3 : lvl);

    float ss = 1.0f / (float)(4 << lvl);
    float x1 = rix1 * ss, y1 = riy1 * ss;
    float rw = fmaxf(rix2 * ss - x1, 1.0f);
    float rh = fmaxf(riy2 * ss - y1, 1.0f);
    float bw = rw * (1.0f / OUT_SZ);
    float bh = rh * (1.0f / OUT_SZ);
    const int H = 800  >> (2 + lvl);
    const int W = 1216 >> (2 + lvl);
    const float fH = (float)H, fW = (float)W;
    const float* fb = (lvl == 0) ? f0 : (lvl == 1) ? f1 : (lvl == 2) ? f2 : f3;
    const int HW = H * W;

    if (lane >= NBINS) return;   // no barriers anywhere -> early exit is safe
    const int bin = lane;
    const int oy = bin / OUT_SZ;
    const int ox = bin - oy * OUT_SZ;

    // ---- x geometry (named scalars only) ----
    float xs0 = x1 + ((float)(2 * ox + 0) + 0.5f) * 0.5f * bw;
    float xs1 = x1 + ((float)(2 * ox + 1) + 0.5f) * 0.5f * bw;
    float fvx0 = (xs0 >= -1.0f && xs0 <= fW) ? 1.0f : 0.0f;
    float fvx1 = (xs1 >= -1.0f && xs1 <= fW) ? 1.0f : 0.0f;
    float xc0 = fminf(fmaxf(xs0, 0.0f), fW - 1.0f);
    float xc1 = fminf(fmaxf(xs1, 0.0f), fW - 1.0f);
    int cx0 = min((int)floorf(xc0), W - 2);
    int cx1 = min((int)floorf(xc1), W - 2);
    float l0 = xc0 - (float)cx0;         // lx in [0,1]; =1.0 at right edge
    float l1 = xc1 - (float)cx1;

    // ---- y geometry ----
    float ys0 = y1 + ((float)(2 * oy + 0) + 0.5f) * 0.5f * bh;
    float ys1 = y1 + ((float)(2 * oy + 1) + 0.5f) * 0.5f * bh;
    float fvy0 = (ys0 >= -1.0f && ys0 <= fH) ? 1.0f : 0.0f;
    float fvy1 = (ys1 >= -1.0f && ys1 <= fH) ? 1.0f : 0.0f;
    float yc0 = fminf(fmaxf(ys0, 0.0f), fH - 1.0f);
    float yc1 = fminf(fmaxf(ys1, 0.0f), fH - 1.0f);
    int ry0 = min((int)floorf(yc0), H - 2);
    int ry1 = min((int)floorf(yc1), H - 2);
    float ly0 = yc0 - (float)ry0;
    float ly1 = yc1 - (float)ry1;

    // row weights (fvy, 0.25 folded); rows r0=ry0, r1=ry0+1, r2=ry1, r3=ry1+1
    float wr0 = 0.25f * fvy0 * (1.0f - ly0);
    float wr1 = 0.25f * fvy0 * ly0;
    float wr2 = 0.25f * fvy1 * (1.0f - ly1);
    float wr3 = 0.25f * fvy1 * ly1;

    int ro0 = ry0 * W, ro1 = ro0 + W;
    int ro2 = ry1 * W, ro3 = ro2 + W;

    const int ch0 = g * 64 + w;         // this wave's first channel
    const float* chp = fb + (size_t)((int)rb * NCH + ch0) * HW;
    float* outp = out + ((size_t)k * NCH + ch0) * NBINS + bin;
    const size_t chstep = 4 * (size_t)HW;

    if ((HW & 3) == 0) {
        // ================= levels 0-2: A=4, W%4==0 =================
        int m0 = cx0 & 3, m1 = cx1 & 3;
        int ax0 = cx0 - m0, ax1 = cx1 - m1;
        bool st0 = (m0 == 3), st1 = (m1 == 3);
        float wq00 = fvx0 * ((m0 == 0) ? (1.0f - l0) : 0.0f);
        float wq01 = fvx0 * ((m0 == 0) ? l0 : (m0 == 1) ? (1.0f - l0) : 0.0f);
        float wq02 = fvx0 * ((m0 == 1) ? l0 : (m0 == 2) ? (1.0f - l0) : 0.0f);
        float wq03 = fvx0 * ((m0 == 2) ? l0 : (m0 == 3) ? (1.0f - l0) : 0.0f);
        float wf0  = fvx0 * ((m0 == 3) ? l0 : 0.0f);
        float wq10 = fvx1 * ((m1 == 0) ? (1.0f - l1) : 0.0f);
        float wq11 = fvx1 * ((m1 == 0) ? l1 : (m1 == 1) ? (1.0f - l1) : 0.0f);
        float wq12 = fvx1 * ((m1 == 1) ? l1 : (m1 == 2) ? (1.0f - l1) : 0.0f);
        float wq13 = fvx1 * ((m1 == 2) ? l1 : (m1 == 3) ? (1.0f - l1) : 0.0f);
        float wf1  = fvx1 * ((m1 == 3) ? l1 : 0.0f);

        int b00 = ro0 + ax0, b01 = ro0 + ax1;
        int b10 = ro1 + ax0, b11 = ro1 + ax1;
        int b20 = ro2 + ax0, b21 = ro2 + ax1;
        int b30 = ro3 + ax0, b31 = ro3 + ax1;
        int x00 = ro0 + cx0 + 1, x01 = ro0 + cx1 + 1;
        int x10 = ro1 + cx0 + 1, x11 = ro1 + cx1 + 1;
        int x20 = ro2 + cx0 + 1, x21 = ro2 + cx1 + 1;
        int x30 = ro3 + cx0 + 1, x31 = ro3 + cx1 + 1;

        const float* p = chp;
        float* o = outp;
#pragma unroll 1
        for (int i = 0; i < 16; ++i) {   // channels ch0, ch0+4, ..., ch0+60
            float4 Q00 = *(const float4*)(p + b00);
            float4 Q01 = *(const float4*)(p + b01);
            float4 Q10 = *(const float4*)(p + b10);
            float4 Q11 = *(const float4*)(p + b11);
            float g00 = st0 ? p[x00] : 0.0f;
            float g10 = st0 ? p[x10] : 0.0f;
            float g01 = st1 ? p[x01] : 0.0f;
            float g11 = st1 ? p[x11] : 0.0f;

            float d00 = Q00.x*wq00 + Q00.y*wq01 + Q00.z*wq02 + Q00.w*wq03 + g00*wf0;
            float d01 = Q01.x*wq10 + Q01.y*wq11 + Q01.z*wq12 + Q01.w*wq13 + g01*wf1;
            float d10 = Q10.x*wq00 + Q10.y*wq01 + Q10.z*wq02 + Q10.w*wq03 + g10*wf0;
            float d11 = Q11.x*wq10 + Q11.y*wq11 + Q11.z*wq12 + Q11.w*wq13 + g11*wf1;
            float acc = wr0 * (d00 + d01) + wr1 * (d10 + d11);

            float4 Q20 = *(const float4*)(p + b20);
            float4 Q21 = *(const float4*)(p + b21);
            float4 Q30 = *(const float4*)(p + b30);
            float4 Q31 = *(const float4*)(p + b31);
            float g20 = st0 ? p[x20] : 0.0f;
            float g30 = st0 ? p[x30] : 0.0f;
            float g21 = st1 ? p[x21] : 0.0f;
            float g31 = st1 ? p[x31] : 0.0f;

            float d20 = Q20.x*wq00 + Q20.y*wq01 + Q20.z*wq02 + Q20.w*wq03 + g20*wf0;
            float d21 = Q21.x*wq10 + Q21.y*wq11 + Q21.z*wq12 + Q21.w*wq13 + g21*wf1;
            float d30 = Q30.x*wq00 + Q30.y*wq01 + Q30.z*wq02 + Q30.w*wq03 + g30*wf0;
            float d31 = Q31.x*wq10 + Q31.y*wq11 + Q31.z*wq12 + Q31.w*wq13 + g31*wf1;
            acc += wr2 * (d20 + d21) + wr3 * (d30 + d31);

            *o = acc;
            p += chstep;
            o += 4 * NBINS;
        }
    } else {
        // ================= level 3: A=2, W%2==0 (W=38) =================
        int m0 = cx0 & 1, m1 = cx1 & 1;
        int ax0 = cx0 - m0, ax1 = cx1 - m1;
        bool st0 = (m0 == 1), st1 = (m1 == 1);
        float wq00 = fvx0 * ((m0 == 0) ? (1.0f - l0) : 0.0f);
        float wq01 = fvx0 * ((m0 == 0) ? l0 : (1.0f - l0));
        float wf0  = fvx0 * ((m0 == 1) ? l0 : 0.0f);
        float wq10 = fvx1 * ((m1 == 0) ? (1.0f - l1) : 0.0f);
        float wq11 = fvx1 * ((m1 == 0) ? l1 : (1.0f - l1));
        float wf1  = fvx1 * ((m1 == 1) ? l1 : 0.0f);

        int b00 = ro0 + ax0, b01 = ro0 + ax1;
        int b10 = ro1 + ax0, b11 = ro1 + ax1;
        int b20 = ro2 + ax0, b21 = ro2 + ax1;
        int b30 = ro3 + ax0, b31 = ro3 + ax1;
        int x00 = ro0 + cx0 + 1, x01 = ro0 + cx1 + 1;
        int x10 = ro1 + cx0 + 1, x11 = ro1 + cx1 + 1;
        int x20 = ro2 + cx0 + 1, x21 = ro2 + cx1 + 1;
        int x30 = ro3 + cx0 + 1, x31 = ro3 + cx1 + 1;

        const float* p = chp;
        float* o = outp;
#pragma unroll 1
        for (int i = 0; i < 16; ++i) {
            float2 Q00 = *(const float2*)(p + b00);
            float2 Q01 = *(const float2*)(p + b01);
            float2 Q10 = *(const float2*)(p + b10);
            float2 Q11 = *(const float2*)(p + b11);
            float g00 = st0 ? p[x00] : 0.0f;
            float g10 = st0 ? p[x10] : 0.0f;
            float g01 = st1 ? p[x01] : 0.0f;
            float g11 = st1 ? p[x11] : 0.0f;
            float d00 = Q00.x*wq00 + Q00.y*wq01 + g00*wf0;
            float d01 = Q01.x*wq10 + Q01.y*wq11 + g01*wf1;
            float d10 = Q10.x*wq00 + Q10.y*wq01 + g10*wf0;
            float d11 = Q11.x*wq10 + Q11.y*wq11 + g11*wf1;
            float acc = wr0 * (d00 + d01) + wr1 * (d10 + d11);

            float2 Q20 = *(const float2*)(p + b20);
            float2 Q21 = *(const float2*)(p + b21);
            float2 Q30 = *(const float2*)(p + b30);
            float2 Q31 = *(const float2*)(p + b31);
            float g20 = st0 ? p[x20] : 0.0f;
            float g30 = st0 ? p[x30] : 0.0f;
            float g21 = st1 ? p[x21] : 0.0f;
            float g31 = st1 ? p[x31] : 0.0f;
            float d20 = Q20.x*wq00 + Q20.y*wq01 + g20*wf0;
            float d21 = Q21.x*wq10 + Q21.y*wq11 + g21*wf1;
            float d30 = Q30.x*wq00 + Q30.y*wq01 + g30*wf0;
            float d31 = Q31.x*wq10 + Q31.y*wq11 + g31*wf1;
            acc += wr2 * (d20 + d21) + wr3 * (d30 + d31);

            *o = acc;
            p += chstep;
            o += 4 * NBINS;
        }
    }
}

// ================================ launch ==================================
extern "C" void kernel_launch(void* const* d_in, const int* in_sizes, int n_in,
                              void* d_out, int out_size, void* d_ws, size_t ws_size,
                              hipStream_t stream)
{
    const float* f0   = (const float*)d_in[0];
    const float* f1   = (const float*)d_in[1];
    const float* f2   = (const float*)d_in[2];
    const float* f3   = (const float*)d_in[3];
    const float* rois = (const float*)d_in[4];
    float* out = (float*)d_out;

    int K = in_sizes[4] / 5;
    if (K <= 0) return;

    int* perm = nullptr;
    if (K <= NBUCK && d_ws && ws_size >= (size_t)K * sizeof(int)) {
        perm = (int*)d_ws;
        roi_sort_kernel<<<1, NBUCK, 0, stream>>>(rois, K, perm);
    }

    roi_align_direct<<<dim3(K, NGROUPS), 256, 0, stream>>>(
        f0, f1, f2, f3, rois, perm, K, out);
}